// Round 1
// baseline (1241.805 us; speedup 1.0000x reference)
//
#include <hip/hip_runtime.h>
#include <cstdint>
#include <cstddef>

// Problem constants
#define BZ    256
#define SRC_N 1024
#define DIM   512
#define CCLIP 10.0f

typedef __bf16 bf16x8 __attribute__((ext_vector_type(8)));
typedef float  floatx4 __attribute__((ext_vector_type(4)));

__device__ __forceinline__ float ftanh(float x) {
  // tanh(x) = 1 - 2/(exp(2x)+1); exp->v_exp, rcp->v_rcp. |rel err| ~1e-6.
  float e = __expf(2.0f * x);
  return 1.0f - 2.0f * __builtin_amdgcn_rcpf(e + 1.0f);
}

__device__ __forceinline__ void gl_lds16(const void* g, void* l) {
  // async global->LDS, 16B/lane. LDS dest = wave-uniform base + lane*16.
  __builtin_amdgcn_global_load_lds(
      (__attribute__((address_space(1))) unsigned int*)g,
      (__attribute__((address_space(3))) unsigned int*)l, 16, 0, 0);
}

// ---------------------------------------------------------------------------
// Kernel A: pack [W_ref; conv_w] -> bf16 (RNE), zero the u accumulator.
// ---------------------------------------------------------------------------
__global__ __launch_bounds__(256) void prep_kernel(
    const float* __restrict__ Wref, const float* __restrict__ convw,
    unsigned short* __restrict__ Wb, float* __restrict__ u) {
  int i = blockIdx.x * 256 + threadIdx.x;      // 0 .. 2*DIM*DIM-1
  const float* sp = (i < DIM * DIM) ? (Wref + i) : (convw + (i - DIM * DIM));
  unsigned int ub = __float_as_uint(*sp);
  unsigned int r = (ub + 0x7fffu + ((ub >> 16) & 1u)) >> 16;   // RNE to bf16
  Wb[i] = (unsigned short)r;
  if (i < BZ * SRC_N) u[i] = 0.0f;
}

// ---------------------------------------------------------------------------
// Kernel B: q[b,e] = sum_d tgt[b,d] * W_q[e,d]   (fp32, tiled)
// grid (8 e-tiles, 32 b-tiles) x 256 threads. Block: 64 e x 8 b.
// ---------------------------------------------------------------------------
__global__ __launch_bounds__(256) void qgemm_kernel(
    const float* __restrict__ tgt, const float* __restrict__ Wq,
    float* __restrict__ q) {
  __shared__ float tgt_s[8 * DIM];       // 16 KB
  __shared__ float Wt[64 * 65];          // padded +1: 2-way banks (free)
  const int t = threadIdx.x;
  const int e0 = blockIdx.x * 64;
  const int b0 = blockIdx.y * 8;

  // stage tgt rows b0..b0+7 (coalesced float4)
  #pragma unroll
  for (int jj = 0; jj < 4; ++jj) {
    int id = jj * 256 + t;               // 1024 float4s total
    int off = id * 4;
    int bl = off >> 9;
    int d = off & 511;
    *(float4*)(tgt_s + off) =
        *(const float4*)(tgt + (size_t)(b0 + bl) * DIM + d);
  }

  const int wave = t >> 6, lane = t & 63;
  float acc0 = 0.f, acc1 = 0.f;
  for (int k0 = 0; k0 < DIM; k0 += 64) {
    __syncthreads();  // protects Wt from previous iter; also covers tgt_s stage
    #pragma unroll
    for (int jj = 0; jj < 4; ++jj) {
      int id = jj * 256 + t;             // 1024 float4s of the 64x64 tile
      int off = id * 4;
      int row = off >> 6;
      int c = off & 63;
      float4 g = *(const float4*)(Wq + (size_t)(e0 + row) * DIM + k0 + c);
      float* wp = Wt + row * 65 + c;
      wp[0] = g.x; wp[1] = g.y; wp[2] = g.z; wp[3] = g.w;
    }
    __syncthreads();
    const float* tg0 = tgt_s + wave * DIM + k0;        // wave-uniform: broadcast
    const float* tg1 = tgt_s + (wave + 4) * DIM + k0;
    const float* wrow = Wt + lane * 65;
    #pragma unroll
    for (int d = 0; d < 64; ++d) {
      float wv = wrow[d];
      acc0 = fmaf(wv, tg0[d], acc0);
      acc1 = fmaf(wv, tg1[d], acc1);
    }
  }
  q[(size_t)(b0 + wave) * DIM + e0 + lane] = acc0;
  q[(size_t)(b0 + wave + 4) * DIM + e0 + lane] = acc1;
}

// ---------------------------------------------------------------------------
// Kernel C: fused batched GEMM  C_b = [W_ref; conv_w] (1024x512) * src_b^T
//   m-tiles 0..3 (e-rows):  partial u[b,s] += sum_e v[e]*tanh(q[b,e]+C)
//   m-tiles 4..7 (o-rows):  attn_h[b,o,s] = C + conv_b[o]   (row-major store)
// 128x128 tile, BK=64, 16x16x32 bf16 MFMA, 4 waves (2x2 of 64x64).
// ---------------------------------------------------------------------------
__global__ __launch_bounds__(256, 2) void fused_gemm_kernel(
    const float* __restrict__ src, const unsigned short* __restrict__ Wb,
    const float* __restrict__ qb, const float* __restrict__ v,
    const float* __restrict__ convb, float* __restrict__ u,
    float* __restrict__ out) {
  __shared__ __align__(16) unsigned short As[128 * 64];   // [m][k] bf16, 16 KB
  __shared__ __align__(16) unsigned short Bs[128 * 64];   // [n][k] bf16, 16 KB

  const int t = threadIdx.x;
  const int lane = t & 63;
  const int wave = t >> 6;
  const int wm = wave & 1, wn = wave >> 1;
  const int b = blockIdx.z;
  const int s0 = blockIdx.x * 128;
  const int m0 = blockIdx.y * 128;

  const float* srcB = src + (size_t)b * SRC_N * DIM;

  floatx4 acc[4][4];
  #pragma unroll
  for (int i = 0; i < 4; ++i)
    #pragma unroll
    for (int j = 0; j < 4; ++j)
      #pragma unroll
      for (int r = 0; r < 4; ++r) acc[i][j][r] = 0.0f;

  const int brow_t = t >> 4;     // 0..15
  const int bcol_t = t & 15;     // *4 floats

  #pragma unroll 1
  for (int kt = 0; kt < 8; ++kt) {
    const int k0 = kt * 64;
    // ---- B (src) global loads: 8 float4/thread, coalesced 256B runs
    float4 bv[8];
    #pragma unroll
    for (int j = 0; j < 8; ++j) {
      const int row = j * 16 + brow_t;
      bv[j] = *(const float4*)(srcB + (size_t)(s0 + row) * DIM + k0 + bcol_t * 4);
    }
    // ---- A (weights) async global->LDS, 1KB/wave-instr, 4 per wave
    #pragma unroll
    for (int ci = 0; ci < 4; ++ci) {
      const int c = wave * 4 + ci;                       // chunk 0..15 = 8 rows
      const unsigned short* g =
          Wb + (size_t)(m0 + c * 8 + (lane >> 3)) * DIM + k0 + (lane & 7) * 8;
      gl_lds16((const void*)g, (void*)(As + c * 512));   // uniform LDS base/wave
    }
    // ---- convert B fp32 -> bf16 (truncate via v_perm) + LDS write
    #pragma unroll
    for (int j = 0; j < 8; ++j) {
      const int row = j * 16 + brow_t;
      unsigned int u0 = __float_as_uint(bv[j].x), u1 = __float_as_uint(bv[j].y);
      unsigned int u2 = __float_as_uint(bv[j].z), u3 = __float_as_uint(bv[j].w);
      uint2 w;
      w.x = __builtin_amdgcn_perm(u1, u0, 0x07060302u);
      w.y = __builtin_amdgcn_perm(u3, u2, 0x07060302u);
      *(uint2*)(Bs + row * 64 + bcol_t * 4) = w;
    }
    __syncthreads();
    // ---- compute: 2 k-steps x 16 MFMA
    #pragma unroll
    for (int ks = 0; ks < 64; ks += 32) {
      bf16x8 af[4], bf[4];
      #pragma unroll
      for (int i = 0; i < 4; ++i)
        af[i] = *(const bf16x8*)(As + (wm * 64 + i * 16 + (lane & 15)) * 64 +
                                 ks + (lane >> 4) * 8);
      #pragma unroll
      for (int j = 0; j < 4; ++j)
        bf[j] = *(const bf16x8*)(Bs + (wn * 64 + j * 16 + (lane & 15)) * 64 +
                                 ks + (lane >> 4) * 8);
      #pragma unroll
      for (int i = 0; i < 4; ++i)
        #pragma unroll
        for (int j = 0; j < 4; ++j)
          acc[i][j] = __builtin_amdgcn_mfma_f32_16x16x32_bf16(
              af[i], bf[j], acc[i][j], 0, 0, 0);
    }
    __syncthreads();
  }

  // ---- epilogue. C/D layout: col = lane&15, row = quad*4 + reg.
  const int quad = lane >> 4;
  const int col = lane & 15;
  if (m0 < DIM) {
    // r-part: u[b,s] += sum_e v[e] * tanh(q[b,e] + r)
    float vv[16], qq[16];
    #pragma unroll
    for (int i = 0; i < 4; ++i)
      #pragma unroll
      for (int r = 0; r < 4; ++r) {
        int e = m0 + wm * 64 + i * 16 + quad * 4 + r;
        vv[i * 4 + r] = v[e];
        qq[i * 4 + r] = qb[(size_t)b * DIM + e];
      }
    #pragma unroll
    for (int j = 0; j < 4; ++j) {
      float p = 0.f;
      #pragma unroll
      for (int i = 0; i < 4; ++i)
        #pragma unroll
        for (int r = 0; r < 4; ++r)
          p += vv[i * 4 + r] * ftanh(qq[i * 4 + r] + acc[i][j][r]);
      p += __shfl_xor(p, 16, 64);
      p += __shfl_xor(p, 32, 64);
      if (lane < 16)
        atomicAdd(u + (size_t)b * SRC_N + s0 + wn * 64 + j * 16 + col, p);
    }
  } else {
    // conv-part: attn_h[b,o,s] = C + conv_b[o]
    #pragma unroll
    for (int i = 0; i < 4; ++i)
      #pragma unroll
      for (int r = 0; r < 4; ++r) {
        int o = m0 - DIM + wm * 64 + i * 16 + quad * 4 + r;
        float cb = convb[o];
        float* op = out + (size_t)b * DIM * SRC_N + (size_t)o * SRC_N + s0 +
                    wn * 64 + col;
        #pragma unroll
        for (int j = 0; j < 4; ++j) op[j * 16] = acc[i][j][r] + cb;
      }
  }
}

// ---------------------------------------------------------------------------
// Kernel D: score = 10*tanh(u); mask (input mask OR s==prev); softmax -> logits;
// also emit mask_ as 0/1 floats. One block per batch.
// ---------------------------------------------------------------------------
__global__ __launch_bounds__(256) void softmax_kernel(
    const float* __restrict__ u, const unsigned char* __restrict__ mask_in,
    const int* __restrict__ prev, float* __restrict__ logits,
    float* __restrict__ mask_out) {
  const int b = blockIdx.x;
  const int t = threadIdx.x;
  const int lane = t & 63, wid = t >> 6;
  __shared__ float sm[4], ss[4];
  const int pv = prev[b];
  const float NEGINF = -__builtin_inff();

  float sc[4], mk[4];
  float mx = NEGINF;
  #pragma unroll
  for (int k = 0; k < 4; ++k) {
    int s = k * 256 + t;
    float uu = u[(size_t)b * SRC_N + s];
    float scv = CCLIP * tanhf(uu);
    bool m = (mask_in[(size_t)b * SRC_N + s] != 0) || (s == pv);
    mk[k] = m ? 1.0f : 0.0f;
    sc[k] = m ? NEGINF : scv;
    mx = fmaxf(mx, sc[k]);
  }
  #pragma unroll
  for (int off = 32; off >= 1; off >>= 1) mx = fmaxf(mx, __shfl_xor(mx, off, 64));
  if (lane == 0) sm[wid] = mx;
  __syncthreads();
  mx = fmaxf(fmaxf(sm[0], sm[1]), fmaxf(sm[2], sm[3]));

  float se = 0.f, ev[4];
  #pragma unroll
  for (int k = 0; k < 4; ++k) {
    ev[k] = __expf(sc[k] - mx);   // exp(-inf)=0 for masked
    se += ev[k];
  }
  #pragma unroll
  for (int off = 32; off >= 1; off >>= 1) se += __shfl_xor(se, off, 64);
  if (lane == 0) ss[wid] = se;
  __syncthreads();
  se = ss[0] + ss[1] + ss[2] + ss[3];
  float inv = 1.0f / se;

  #pragma unroll
  for (int k = 0; k < 4; ++k) {
    int s = k * 256 + t;
    logits[(size_t)b * SRC_N + s] = ev[k] * inv;
    mask_out[(size_t)b * SRC_N + s] = mk[k];
  }
}

// ---------------------------------------------------------------------------
extern "C" void kernel_launch(void* const* d_in, const int* in_sizes, int n_in,
                              void* d_out, int out_size, void* d_ws,
                              size_t ws_size, hipStream_t stream) {
  const float* src          = (const float*)d_in[0];
  const float* tgt          = (const float*)d_in[1];
  const unsigned char* mask = (const unsigned char*)d_in[2];
  const int* prev           = (const int*)d_in[3];
  const float* Wq           = (const float*)d_in[4];
  const float* Wref         = (const float*)d_in[5];
  const float* v            = (const float*)d_in[6];
  const float* convw        = (const float*)d_in[7];
  const float* convb        = (const float*)d_in[8];
  float* out = (float*)d_out;

  // ws layout: Wb bf16 1MB | q 512KB | u 1MB  (total 2.5 MB)
  char* ws = (char*)d_ws;
  unsigned short* Wb = (unsigned short*)ws;
  float* q = (float*)(ws + (1u << 20));
  float* u = (float*)(ws + (1u << 20) + (512u << 10));

  float* attn     = out;                                  // (B, D, S)
  float* logits   = out + (size_t)BZ * DIM * SRC_N;       // (B, 1, S)
  float* mask_out = logits + (size_t)BZ * SRC_N;          // (B, 1, S) as 0/1

  prep_kernel<<<2048, 256, 0, stream>>>(Wref, convw, Wb, u);
  qgemm_kernel<<<dim3(8, 32), 256, 0, stream>>>(tgt, Wq, q);
  fused_gemm_kernel<<<dim3(8, 8, BZ), 256, 0, stream>>>(src, Wb, q, v, convb, u,
                                                        attn);
  softmax_kernel<<<BZ, 256, 0, stream>>>(u, mask, prev, logits, mask_out);
}